// Round 10
// baseline (383.483 us; speedup 1.0000x reference)
//
#include <hip/hip_runtime.h>

// Problem constants (B=8, T=4096, D=64, M=1024, N=32768)
#define T_DIM 4096
#define D_DIM 64
#define M_DIM 1024
#define N_ROWS 32768
#define TR 16   // rows (tokens) per workgroup
#define NT 512  // threads per block (8 waves)
#define NW 8    // waves

typedef __attribute__((ext_vector_type(8))) short bf16x8;
typedef __attribute__((ext_vector_type(4))) float f32x4;

// ws layout: floats [0,1024)=||e||^2, [1024,2048)=counts, [2048]=loss accum.
// shorts from float index 4096: EH[65536], EL[65536], ETH[65536], ETL[65536]
#define WS_BF16_OFF 4096

__device__ __forceinline__ short f2bfs(float f) {
  union { float f; unsigned u; } v; v.f = f;
  unsigned r = v.u + 0x7fffu + ((v.u >> 16) & 1u);  // RNE
  return (short)(r >> 16);
}
__device__ __forceinline__ float bf2f(short h) {
  union { unsigned u; float f; } v; v.u = ((unsigned)(unsigned short)h) << 16;
  return v.f;
}
// 8 consecutive fp32 -> hi/lo bf16x8
__device__ __forceinline__ void cvt8(const float* p, bf16x8& h8, bf16x8& l8) {
  float4 a = *(const float4*)p, b = *(const float4*)(p + 4);
  float v[8] = {a.x, a.y, a.z, a.w, b.x, b.y, b.z, b.w};
#pragma unroll
  for (int i = 0; i < 8; ++i) {
    short h = f2bfs(v[i]);
    h8[i] = h;
    l8[i] = f2bfs(v[i] - bf2f(h));
  }
}

// split embedding into hi/lo bf16 (row-major + transposed), ||e||^2, zeroing
__global__ void vq_conv(const float* __restrict__ emb, float* __restrict__ ws) {
  __shared__ short s_h[64][72], s_l[64][72];
  const int tid = threadIdx.x;
  const int mb = blockIdx.x * 64;  // 16 blocks x 64 codebook rows
  short* EH = (short*)(ws + WS_BF16_OFF);
  short* EL = EH + 65536;
  short* ETH = EL + 65536;
  short* ETL = ETH + 65536;
#pragma unroll
  for (int i = 0; i < 16; ++i) {
    int lin = tid + 256 * i;  // 0..4095 over (ml, d)
    int ml = lin >> 6, d = lin & 63;
    float v = emb[(size_t)(mb + ml) * 64 + d];
    short h = f2bfs(v);
    short l = f2bfs(v - bf2f(h));
    EH[(size_t)(mb + ml) * 64 + d] = h;
    EL[(size_t)(mb + ml) * 64 + d] = l;
    s_h[d][ml] = h;
    s_l[d][ml] = l;
  }
  if (tid < 64) {
    const float* e = emb + (size_t)(mb + tid) * 64;
    float s = 0.f;
#pragma unroll
    for (int d = 0; d < 64; d += 4) {
      float4 v = *(const float4*)(e + d);
      s += v.x * v.x + v.y * v.y + v.z * v.z + v.w * v.w;
    }
    ws[mb + tid] = s;
    ws[M_DIM + mb + tid] = 0.f;
  }
  if (blockIdx.x == 0 && tid == 0) ws[2 * M_DIM] = 0.f;
  __syncthreads();
#pragma unroll
  for (int i = 0; i < 16; ++i) {
    int lin = tid + 256 * i;  // now (d, ml)
    int d = lin >> 6, ml = lin & 63;
    ETH[(size_t)d * 1024 + mb + ml] = s_h[d][ml];
    ETL[(size_t)d * 1024 + mb + ml] = s_l[d][ml];
  }
}

// __launch_bounds__(512, 2): 2 waves/EU floor -> up to 256 VGPRs.
// R8/R9 proved the spill (WRITE_SIZE 9.3 -> 116 MB) is the RA pinned at the
// 64-VGPR tier by (512,4) — 4 co-resident 8-wave blocks — while LDS (42.5 KB)
// caps us at 3 blocks/CU anyway, so the 64-reg constraint bought nothing.
// True pressure of the fused single-barrier kernel is ~90-110 regs.
__global__ __launch_bounds__(NT, 2) void vq_main(
    const float* __restrict__ x, const float* __restrict__ emb,
    const float* __restrict__ lvq, const float* __restrict__ gum,
    const float* __restrict__ temp, float* __restrict__ outq,
    float* __restrict__ ws) {
  __shared__ float s_x[TR][68];          // x tile (padded)
  __shared__ float s_qp[NW][TR][68];     // per-wave: P chunk transpose, then q partials
  __shared__ float4 s_st1[NW][TR];       // per-wave (mlocal, argmax_bits, Zs_w, As_w)
  __shared__ float2 s_st2[NW][TR];       // per-wave (Gm_w, Zg_w)
  __shared__ float s_red[NW];

  const int tid = threadIdx.x;
  const int lane = tid & 63;
  const int wl = tid >> 6;     // wave 0..7 : owns m/K range [128*wl, 128*wl+128)
  const int mq = lane >> 4;    // quad 0..3
  const int mn = lane & 15;
  const int n0 = blockIdx.x * TR;
  const int b = n0 >> 12;
  const int t0 = n0 & (T_DIM - 1);
  const float precision = __expf(-lvq[0]);
  const float halfprec = 0.5f * precision;
  const float inv_temp = 1.0f / temp[0];
  const float* eew = ws;
  float* counts = ws + M_DIM;
  float* accum = ws + 2 * M_DIM;
  const short* EH = (const short*)(ws + WS_BF16_OFF);
  const short* EL = EH + 65536;
  const short* ETH = EL + 65536;
  const short* ETL = ETH + 65536;

  // ---- stage x tile: x[b][d][t0+tt] ----
  {
    int tt = tid & 15, d0 = tid >> 4;  // d0 in [0,32)
    s_x[tt][d0] = x[((size_t)b << 18) + ((size_t)d0 << 12) + (size_t)(t0 + tt)];
    s_x[tt][d0 + 32] =
        x[((size_t)b << 18) + ((size_t)(d0 + 32) << 12) + (size_t)(t0 + tt)];
  }
  __syncthreads();
  // ||x||^2 is a per-token (row) constant in the distance; it cancels in
  // argmin, softmax, log_softmax, and entropy -> dropped entirely.

  // ---- GEMM1 (MFMA): shifted logits in REGISTERS
  // (C layout: col=mn->m, row=mq*4+reg->token)
  // wave wl: 8 m-tiles of 16; K=64 = 2 k-steps; 32 score VGPRs/thread
  f32x4 acc[8];
  {
    bf16x8 ah0, al0, ah1, al1;
    cvt8(&s_x[mn][mq * 8], ah0, al0);        // k-step 0
    cvt8(&s_x[mn][32 + mq * 8], ah1, al1);   // k-step 1
#pragma unroll
    for (int tt = 0; tt < 8; ++tt) acc[tt] = (f32x4){0.f, 0.f, 0.f, 0.f};
#pragma unroll
    for (int tt = 0; tt < 8; ++tt) {
      int m0 = wl * 128 + tt * 16;
      const short* bp = EH + (m0 + mn) * 64 + mq * 8;
      const short* lp = EL + (m0 + mn) * 64 + mq * 8;
      bf16x8 bh0 = *(const bf16x8*)bp;
      bf16x8 bh1 = *(const bf16x8*)(bp + 32);
      bf16x8 bl0 = *(const bf16x8*)lp;
      bf16x8 bl1 = *(const bf16x8*)(lp + 32);
      acc[tt] = __builtin_amdgcn_mfma_f32_16x16x32_bf16(ah0, bh0, acc[tt], 0, 0, 0);
      acc[tt] = __builtin_amdgcn_mfma_f32_16x16x32_bf16(ah1, bh1, acc[tt], 0, 0, 0);
      acc[tt] = __builtin_amdgcn_mfma_f32_16x16x32_bf16(al0, bh0, acc[tt], 0, 0, 0);
      acc[tt] = __builtin_amdgcn_mfma_f32_16x16x32_bf16(al1, bh1, acc[tt], 0, 0, 0);
      acc[tt] = __builtin_amdgcn_mfma_f32_16x16x32_bf16(ah0, bl0, acc[tt], 0, 0, 0);
      acc[tt] = __builtin_amdgcn_mfma_f32_16x16x32_bf16(ah1, bl1, acc[tt], 0, 0, 0);
    }
  }

  // ---- epilogue: s = prec*dot - 0.5*prec*||e||^2 (no xx term) ----
#pragma unroll
  for (int tt = 0; tt < 8; ++tt) {
    float eev = eew[wl * 128 + tt * 16 + mn];
#pragma unroll
    for (int reg = 0; reg < 4; ++reg)
      acc[tt][reg] = precision * acc[tt][reg] - halfprec * eev;
  }

  // ---- PER-REG fused stats phase (no barrier). With the 128+ VGPR budget
  // the scheduler is free to hoist the next reg's gumbel loads under the
  // current reg's exp chain — prefetch in REAL registers, not scratch.
  float Gm[4];
#pragma unroll
  for (int reg = 0; reg < 4; ++reg) {
    // wave-local max + argmax over this wave's 128 codes
    float mx = acc[0][reg]; int ix = wl * 128 + mn;
#pragma unroll
    for (int tt = 1; tt < 8; ++tt) {
      float v = acc[tt][reg];
      int m = wl * 128 + tt * 16 + mn;
      if (v > mx) { mx = v; ix = m; }
    }
#pragma unroll
    for (int off = 1; off <= 8; off <<= 1) {
      float omx = __shfl_xor(mx, off);
      int oix = __shfl_xor(ix, off);
      if (omx > mx || (omx == mx && oix < ix)) { mx = omx; ix = oix; }
    }
    // transform: entropy partials + gumbelize in-place + local gumbel max
    const float* gp = gum + ((size_t)(n0 + mq * 4 + reg) << 10) + wl * 128 + mn;
    float zs = 0.f, as = 0.f, gm = -1e30f;
#pragma unroll
    for (int tt = 0; tt < 8; ++tt) {
      float g = gp[tt * 16];
      float s = acc[tt][reg];
      float a = s - mx;
      float e = __expf(a);
      zs += e; as += a * e;
      float gv = (s + g) * inv_temp;
      acc[tt][reg] = gv;
      gm = fmaxf(gm, gv);
    }
#pragma unroll
    for (int off = 1; off <= 8; off <<= 1) {
      zs += __shfl_xor(zs, off);
      as += __shfl_xor(as, off);
      gm = fmaxf(gm, __shfl_xor(gm, off));
    }
    // second exp pass with wave-local gumbel max; local Zg
    float zg = 0.f;
#pragma unroll
    for (int tt = 0; tt < 8; ++tt) {
      float p = __expf(acc[tt][reg] - gm);
      acc[tt][reg] = p;
      zg += p;
    }
#pragma unroll
    for (int off = 1; off <= 8; off <<= 1) zg += __shfl_xor(zg, off);
    if (mn == 0) {
      s_st1[wl][mq * 4 + reg] = make_float4(mx, __int_as_float(ix), zs, as);
      s_st2[wl][mq * 4 + reg] = make_float2(gm, zg);
    }
    Gm[reg] = gm;
  }
  __syncthreads();

  // ---- combine: global max/argmax, rescaled Zs/As, global gumbel max/Zg ----
  float invZg[4];
  float partial = 0.f;
#pragma unroll
  for (int reg = 0; reg < 4; ++reg) {
    int token = mq * 4 + reg;
    float M = -1e30f; int bi = 0x7fffffff;
#pragma unroll
    for (int w = 0; w < NW; ++w) {
      float4 v = s_st1[w][token];
      int iv = __float_as_int(v.y);
      if (v.x > M || (v.x == M && iv < bi)) { M = v.x; bi = iv; }
    }
    float zs = 0.f, as = 0.f;
#pragma unroll
    for (int w = 0; w < NW; ++w) {
      float4 v = s_st1[w][token];
      float d = v.x - M;
      float ed = __expf(d);
      zs += ed * v.z;
      as += ed * (v.w + d * v.z);
    }
    float GM = -1e30f;
#pragma unroll
    for (int w = 0; w < NW; ++w) GM = fmaxf(GM, s_st2[w][token].x);
    float zg = 0.f;
#pragma unroll
    for (int w = 0; w < NW; ++w) {
      float2 u = s_st2[w][token];
      zg += u.y * __expf(u.x - GM);
    }
    // fold this wave's rescale exp(Gm_w - GM) into the normalizer
    invZg[reg] = __expf(Gm[reg] - GM) / zg;
    if (wl == 0 && mn == 0) {
      partial += as / zs - __logf(zs);
      atomicAdd(counts + bi, 1.0f);
    }
  }

  // ---- GEMM2 (MFMA): q[token][d] += P[token][k-chunk] * E[k-chunk][d]
  // wave wl owns K-range [128wl, 128wl+128) = 4 k-steps of 32
  {
    f32x4 q[4];
#pragma unroll
    for (int nt = 0; nt < 4; ++nt) q[nt] = (f32x4){0.f, 0.f, 0.f, 0.f};
    float* sp = &s_qp[wl][0][0];  // stride-36 scratch during transpose
#pragma unroll
    for (int ks = 0; ks < 4; ++ks) {
#pragma unroll
      for (int reg = 0; reg < 4; ++reg) {
        sp[(mq * 4 + reg) * 36 + mn]      = acc[2 * ks][reg] * invZg[reg];
        sp[(mq * 4 + reg) * 36 + 16 + mn] = acc[2 * ks + 1][reg] * invZg[reg];
      }
      bf16x8 ph, pl;
      cvt8(&sp[mn * 36 + mq * 8], ph, pl);  // A row = token mn, k = mq*8+j
      int k0 = wl * 128 + ks * 32;
#pragma unroll
      for (int nt = 0; nt < 4; ++nt) {
        const short* bp = ETH + (nt * 16 + mn) * 1024 + k0 + mq * 8;
        const short* lp = ETL + (nt * 16 + mn) * 1024 + k0 + mq * 8;
        bf16x8 bh = *(const bf16x8*)bp;
        bf16x8 bl = *(const bf16x8*)lp;
        q[nt] = __builtin_amdgcn_mfma_f32_16x16x32_bf16(ph, bh, q[nt], 0, 0, 0);
        q[nt] = __builtin_amdgcn_mfma_f32_16x16x32_bf16(pl, bh, q[nt], 0, 0, 0);
        q[nt] = __builtin_amdgcn_mfma_f32_16x16x32_bf16(ph, bl, q[nt], 0, 0, 0);
      }
    }
    // q partials -> own LDS region (C layout: token = mq*4+reg, d = nt*16+mn)
#pragma unroll
    for (int nt = 0; nt < 4; ++nt)
#pragma unroll
      for (int reg = 0; reg < 4; ++reg)
        s_qp[wl][mq * 4 + reg][nt * 16 + mn] = q[nt][reg];
  }
  __syncthreads();

  // ---- combine K-split partials, write quantized (transposed), recon ----
  // all 512 threads: 2 d-columns each
  {
    int r = tid & 15, dq = tid >> 4;  // consecutive lanes -> consecutive t
    int d = dq * 2;
    float2 qs = {0.f, 0.f};
#pragma unroll
    for (int w = 0; w < NW; ++w) {
      float2 v = *(const float2*)&s_qp[w][r][d];
      qs.x += v.x; qs.y += v.y;
    }
    int t = t0 + r;
    float* ob = outq + ((size_t)b << 18) + (size_t)t;
    ob[(size_t)(d + 0) << 12] = qs.x;
    ob[(size_t)(d + 1) << 12] = qs.y;
    float2 xv = *(const float2*)&s_x[r][d];
    float dx0 = xv.x - qs.x, dx1 = xv.y - qs.y;
    partial += 0.5f * precision * (dx0 * dx0 + dx1 * dx1);
  }
#pragma unroll
  for (int off = 32; off; off >>= 1) partial += __shfl_xor(partial, off);
  if (lane == 0) s_red[wl] = partial;
  __syncthreads();
  if (tid == 0) {
    float s = 0.f;
#pragma unroll
    for (int w = 0; w < NW; ++w) s += s_red[w];
    atomicAdd(accum, s);
  }
}

__global__ void vq_finalize(const float* __restrict__ ws, float* __restrict__ out) {
  __shared__ float red[4];
  int tid = threadIdx.x;
  float h = 0.f;
  for (int m = tid; m < M_DIM; m += 256) {
    float avg = ws[M_DIM + m] * (1.0f / 32768.0f);
    h += avg * __logf(avg + 1e-10f);
  }
#pragma unroll
  for (int off = 32; off; off >>= 1) h += __shfl_xor(h, off);
  int lane = tid & 63, wave = tid >> 6;
  if (lane == 0) red[wave] = h;
  __syncthreads();
  if (tid == 0) {
    out[0] = ws[2 * M_DIM] * 0.125f;                        // loss = total / B
    out[1] = __expf(-(red[0] + red[1] + red[2] + red[3]));  // perplexity
  }
}

extern "C" void kernel_launch(void* const* d_in, const int* in_sizes, int n_in,
                              void* d_out, int out_size, void* d_ws, size_t ws_size,
                              hipStream_t stream) {
  const float* x = (const float*)d_in[0];
  const float* emb = (const float*)d_in[1];
  const float* lvq = (const float*)d_in[2];
  const float* gum = (const float*)d_in[3];
  const float* temp = (const float*)d_in[4];
  float* out = (float*)d_out;
  float* ws = (float*)d_ws;

  hipLaunchKernelGGL(vq_conv, dim3(16), dim3(256), 0, stream, emb, ws);
  hipLaunchKernelGGL(vq_main, dim3(N_ROWS / TR), dim3(NT), 0, stream,
                     x, emb, lvq, gum, temp, out, ws);
  hipLaunchKernelGGL(vq_finalize, dim3(1), dim3(256), 0, stream, ws,
                     out + (size_t)2097152);
}

// Round 11
// 318.743 us; speedup vs baseline: 1.2031x; 1.2031x over previous
//
#include <hip/hip_runtime.h>

// Problem constants (B=8, T=4096, D=64, M=1024, N=32768)
#define T_DIM 4096
#define D_DIM 64
#define M_DIM 1024
#define N_ROWS 32768
#define TR 16   // rows (tokens) per workgroup
#define NT 512  // threads per block (8 waves)
#define NW 8    // waves

typedef __attribute__((ext_vector_type(8))) short bf16x8;
typedef __attribute__((ext_vector_type(4))) float f32x4;

// ws layout: floats [0,1024)=||e||^2, [1024,2048)=counts, [2048]=loss accum.
// shorts from float index 4096: EH[65536], EL[65536], ETH[65536], ETL[65536]
#define WS_BF16_OFF 4096

__device__ __forceinline__ short f2bfs(float f) {
  union { float f; unsigned u; } v; v.f = f;
  unsigned r = v.u + 0x7fffu + ((v.u >> 16) & 1u);  // RNE
  return (short)(r >> 16);
}
__device__ __forceinline__ float bf2f(short h) {
  union { unsigned u; float f; } v; v.u = ((unsigned)(unsigned short)h) << 16;
  return v.f;
}
// 8 consecutive fp32 -> hi/lo bf16x8
__device__ __forceinline__ void cvt8(const float* p, bf16x8& h8, bf16x8& l8) {
  float4 a = *(const float4*)p, b = *(const float4*)(p + 4);
  float v[8] = {a.x, a.y, a.z, a.w, b.x, b.y, b.z, b.w};
#pragma unroll
  for (int i = 0; i < 8; ++i) {
    short h = f2bfs(v[i]);
    h8[i] = h;
    l8[i] = f2bfs(v[i] - bf2f(h));
  }
}

// split embedding into hi/lo bf16 (row-major + transposed), ||e||^2, zeroing
__global__ void vq_conv(const float* __restrict__ emb, float* __restrict__ ws) {
  __shared__ short s_h[64][72], s_l[64][72];
  const int tid = threadIdx.x;
  const int mb = blockIdx.x * 64;  // 16 blocks x 64 codebook rows
  short* EH = (short*)(ws + WS_BF16_OFF);
  short* EL = EH + 65536;
  short* ETH = EL + 65536;
  short* ETL = ETH + 65536;
#pragma unroll
  for (int i = 0; i < 16; ++i) {
    int lin = tid + 256 * i;  // 0..4095 over (ml, d)
    int ml = lin >> 6, d = lin & 63;
    float v = emb[(size_t)(mb + ml) * 64 + d];
    short h = f2bfs(v);
    short l = f2bfs(v - bf2f(h));
    EH[(size_t)(mb + ml) * 64 + d] = h;
    EL[(size_t)(mb + ml) * 64 + d] = l;
    s_h[d][ml] = h;
    s_l[d][ml] = l;
  }
  if (tid < 64) {
    const float* e = emb + (size_t)(mb + tid) * 64;
    float s = 0.f;
#pragma unroll
    for (int d = 0; d < 64; d += 4) {
      float4 v = *(const float4*)(e + d);
      s += v.x * v.x + v.y * v.y + v.z * v.z + v.w * v.w;
    }
    ws[mb + tid] = s;
    ws[M_DIM + mb + tid] = 0.f;
  }
  if (blockIdx.x == 0 && tid == 0) ws[2 * M_DIM] = 0.f;
  __syncthreads();
#pragma unroll
  for (int i = 0; i < 16; ++i) {
    int lin = tid + 256 * i;  // now (d, ml)
    int d = lin >> 6, ml = lin & 63;
    ETH[(size_t)d * 1024 + mb + ml] = s_h[d][ml];
    ETL[(size_t)d * 1024 + mb + ml] = s_l[d][ml];
  }
}

// (512,4): empirically pins the 64-VGPR tier (8 waves/SIMD). This structure
// (R0 phase-split) fits: round-2 variant measured 64 VGPR with a 32-wide
// prefetch on top; without it, pressure ~56. LDS trimmed to 40,224 B
// (< 160KiB/4 = 40,960) -> 4 blocks/CU static occupancy, up from 3.
__global__ __launch_bounds__(NT, 4) void vq_main(
    const float* __restrict__ x, const float* __restrict__ emb,
    const float* __restrict__ lvq, const float* __restrict__ gum,
    const float* __restrict__ temp, float* __restrict__ outq,
    float* __restrict__ ws) {
  __shared__ float s_x[TR][68];          // x tile (padded)                4352 B
  __shared__ float s_qp[NW][TR][64];     // P transpose scratch + q partials 32768 B
  __shared__ float2 s_stA[NW][TR];       // per-wave (max, argmax bits)    1024 B
  __shared__ float4 s_stB[NW][TR];       // per-wave (Zs, As, Gm_w, Zg_w)  2048 B
  __shared__ float s_red[NW];            //                                  32 B

  const int tid = threadIdx.x;
  const int lane = tid & 63;
  const int wl = tid >> 6;     // wave 0..7 : owns m/K range [128*wl, 128*wl+128)
  const int mq = lane >> 4;    // quad 0..3
  const int mn = lane & 15;
  const int n0 = blockIdx.x * TR;
  const int b = n0 >> 12;
  const int t0 = n0 & (T_DIM - 1);
  const float precision = __expf(-lvq[0]);
  const float halfprec = 0.5f * precision;
  const float inv_temp = 1.0f / temp[0];
  const float* eew = ws;
  float* counts = ws + M_DIM;
  float* accum = ws + 2 * M_DIM;
  const short* EH = (const short*)(ws + WS_BF16_OFF);
  const short* EL = EH + 65536;
  const short* ETH = EL + 65536;
  const short* ETL = ETH + 65536;

  // ---- stage x tile: x[b][d][t0+tt] ----
  {
    int tt = tid & 15, d0 = tid >> 4;  // d0 in [0,32)
    s_x[tt][d0] = x[((size_t)b << 18) + ((size_t)d0 << 12) + (size_t)(t0 + tt)];
    s_x[tt][d0 + 32] =
        x[((size_t)b << 18) + ((size_t)(d0 + 32) << 12) + (size_t)(t0 + tt)];
  }
  __syncthreads();
  // ||x||^2 is a per-token (row) constant in the distance; it cancels in
  // argmin, softmax, log_softmax, and entropy -> dropped entirely.

  // ---- GEMM1 (MFMA): shifted logits in REGISTERS
  // (C layout: col=mn->m, row=mq*4+reg->token)
  f32x4 acc[8];
  {
    bf16x8 ah0, al0, ah1, al1;
    cvt8(&s_x[mn][mq * 8], ah0, al0);        // k-step 0
    cvt8(&s_x[mn][32 + mq * 8], ah1, al1);   // k-step 1
#pragma unroll
    for (int tt = 0; tt < 8; ++tt) acc[tt] = (f32x4){0.f, 0.f, 0.f, 0.f};
#pragma unroll
    for (int tt = 0; tt < 8; ++tt) {
      int m0 = wl * 128 + tt * 16;
      const short* bp = EH + (m0 + mn) * 64 + mq * 8;
      const short* lp = EL + (m0 + mn) * 64 + mq * 8;
      bf16x8 bh0 = *(const bf16x8*)bp;
      bf16x8 bh1 = *(const bf16x8*)(bp + 32);
      bf16x8 bl0 = *(const bf16x8*)lp;
      bf16x8 bl1 = *(const bf16x8*)(lp + 32);
      acc[tt] = __builtin_amdgcn_mfma_f32_16x16x32_bf16(ah0, bh0, acc[tt], 0, 0, 0);
      acc[tt] = __builtin_amdgcn_mfma_f32_16x16x32_bf16(ah1, bh1, acc[tt], 0, 0, 0);
      acc[tt] = __builtin_amdgcn_mfma_f32_16x16x32_bf16(al0, bh0, acc[tt], 0, 0, 0);
      acc[tt] = __builtin_amdgcn_mfma_f32_16x16x32_bf16(al1, bh1, acc[tt], 0, 0, 0);
      acc[tt] = __builtin_amdgcn_mfma_f32_16x16x32_bf16(ah0, bl0, acc[tt], 0, 0, 0);
      acc[tt] = __builtin_amdgcn_mfma_f32_16x16x32_bf16(ah1, bl1, acc[tt], 0, 0, 0);
    }
  }

  // ---- epilogue: s = prec*dot - 0.5*prec*||e||^2 (no xx term) ----
#pragma unroll
  for (int tt = 0; tt < 8; ++tt) {
    float eev = eew[wl * 128 + tt * 16 + mn];
#pragma unroll
    for (int reg = 0; reg < 4; ++reg)
      acc[tt][reg] = precision * acc[tt][reg] - halfprec * eev;
  }

  // ---- R1: wave-local max/argmax -> LDS -> barrier -> global ----
#pragma unroll
  for (int reg = 0; reg < 4; ++reg) {
    float mx = acc[0][reg]; int ix = wl * 128 + mn;
#pragma unroll
    for (int tt = 1; tt < 8; ++tt) {
      float v = acc[tt][reg];
      int m = wl * 128 + tt * 16 + mn;
      if (v > mx) { mx = v; ix = m; }
    }
#pragma unroll
    for (int off = 1; off <= 8; off <<= 1) {
      float omx = __shfl_xor(mx, off);
      int oix = __shfl_xor(ix, off);
      if (omx > mx || (omx == mx && oix < ix)) { mx = omx; ix = oix; }
    }
    if (mn == 0) s_stA[wl][mq * 4 + reg] = make_float2(mx, __int_as_float(ix));
  }
  __syncthreads();
  float Mx[4];
  float partial = 0.f;
#pragma unroll
  for (int reg = 0; reg < 4; ++reg) {
    int token = mq * 4 + reg;
    float2 a0 = s_stA[0][token];
    float mx = a0.x; int mi = __float_as_int(a0.y);
#pragma unroll
    for (int w = 1; w < NW; ++w) {
      float2 aw = s_stA[w][token];
      int i2 = __float_as_int(aw.y);
      if (aw.x > mx || (aw.x == mx && i2 < mi)) { mx = aw.x; mi = i2; }
    }
    Mx[reg] = mx;
    if (wl == 0 && mn == 0) atomicAdd(counts + mi, 1.0f);
  }

  // ---- transform with GLOBAL max: entropy partials + gumbelize in-place +
  // local gumbel max. Gumbels loaded in-loop (R0-verified, no spill). ----
  float Zs[4], As[4], Gm[4];
#pragma unroll
  for (int reg = 0; reg < 4; ++reg) {
    const float* gp = gum + ((size_t)(n0 + mq * 4 + reg) << 10) + wl * 128 + mn;
    float zs = 0.f, as = 0.f, gm = -1e30f;
#pragma unroll
    for (int tt = 0; tt < 8; ++tt) {
      float g = gp[tt * 16];
      float s = acc[tt][reg];
      float a = s - Mx[reg];
      float e = __expf(a);
      zs += e; as += a * e;
      float gv = (s + g) * inv_temp;
      acc[tt][reg] = gv;
      gm = fmaxf(gm, gv);
    }
    Zs[reg] = zs; As[reg] = as; Gm[reg] = gm;
  }
  // intra-wave reduce (Zs, As, gm)
#pragma unroll
  for (int reg = 0; reg < 4; ++reg) {
#pragma unroll
    for (int off = 1; off <= 8; off <<= 1) {
      Zs[reg] += __shfl_xor(Zs[reg], off);
      As[reg] += __shfl_xor(As[reg], off);
      Gm[reg] = fmaxf(Gm[reg], __shfl_xor(Gm[reg], off));
    }
  }
  // ---- second exp pass with wave-local gumbel max; local Zg; single write ----
#pragma unroll
  for (int reg = 0; reg < 4; ++reg) {
    float zg = 0.f;
#pragma unroll
    for (int tt = 0; tt < 8; ++tt) {
      float p = __expf(acc[tt][reg] - Gm[reg]);
      acc[tt][reg] = p;
      zg += p;
    }
#pragma unroll
    for (int off = 1; off <= 8; off <<= 1) zg += __shfl_xor(zg, off);
    if (mn == 0)
      s_stB[wl][mq * 4 + reg] = make_float4(Zs[reg], As[reg], Gm[reg], zg);
  }
  __syncthreads();

  // ---- combine: Zs/As straight sums (global max), gumbel max/Zg rescale ----
  float invZg[4];
#pragma unroll
  for (int reg = 0; reg < 4; ++reg) {
    int token = mq * 4 + reg;
    float zs = 0.f, as = 0.f, GM = -1e30f;
#pragma unroll
    for (int w = 0; w < NW; ++w) GM = fmaxf(GM, s_stB[w][token].z);
#pragma unroll
    for (int w = 0; w < NW; ++w) {
      float4 v = s_stB[w][token];
      zs += v.x; as += v.y;
    }
    float zg = 0.f;
#pragma unroll
    for (int w = 0; w < NW; ++w) {
      float4 v = s_stB[w][token];
      zg += v.w * __expf(v.z - GM);
    }
    // fold this wave's rescale exp(Gm_w - GM) into the normalizer
    invZg[reg] = __expf(Gm[reg] - GM) / zg;
    if (wl == 0 && mn == 0) partial += as / zs - __logf(zs);
  }

  // ---- GEMM2 (MFMA): q[token][d] += P[token][k-chunk] * E[k-chunk][d]
  // wave wl owns K-range [128wl, 128wl+128) = 4 k-steps of 32
  {
    f32x4 q[4];
#pragma unroll
    for (int nt = 0; nt < 4; ++nt) q[nt] = (f32x4){0.f, 0.f, 0.f, 0.f};
    float* sp = &s_qp[wl][0][0];  // stride-36 flat scratch during transpose
#pragma unroll
    for (int ks = 0; ks < 4; ++ks) {
#pragma unroll
      for (int reg = 0; reg < 4; ++reg) {
        sp[(mq * 4 + reg) * 36 + mn]      = acc[2 * ks][reg] * invZg[reg];
        sp[(mq * 4 + reg) * 36 + 16 + mn] = acc[2 * ks + 1][reg] * invZg[reg];
      }
      bf16x8 ph, pl;
      cvt8(&sp[mn * 36 + mq * 8], ph, pl);  // A row = token mn, k = mq*8+j
      int k0 = wl * 128 + ks * 32;
#pragma unroll
      for (int nt = 0; nt < 4; ++nt) {
        const short* bp = ETH + (nt * 16 + mn) * 1024 + k0 + mq * 8;
        const short* lp = ETL + (nt * 16 + mn) * 1024 + k0 + mq * 8;
        bf16x8 bh = *(const bf16x8*)bp;
        bf16x8 bl = *(const bf16x8*)lp;
        q[nt] = __builtin_amdgcn_mfma_f32_16x16x32_bf16(ph, bh, q[nt], 0, 0, 0);
        q[nt] = __builtin_amdgcn_mfma_f32_16x16x32_bf16(pl, bh, q[nt], 0, 0, 0);
        q[nt] = __builtin_amdgcn_mfma_f32_16x16x32_bf16(ph, bl, q[nt], 0, 0, 0);
      }
    }
    // q partials: rotation swizzle col=(d+4r)&63 gives the SAME bank pattern
    // the old +68 pad gave ((4r+d)%32), at 64 width -> 2 KB LDS saved.
#pragma unroll
    for (int nt = 0; nt < 4; ++nt)
#pragma unroll
      for (int reg = 0; reg < 4; ++reg) {
        int r = mq * 4 + reg, d = nt * 16 + mn;
        s_qp[wl][r][(d + 4 * r) & 63] = q[nt][reg];
      }
  }
  __syncthreads();

  // ---- combine K-split partials, write quantized (transposed), recon ----
  // all 512 threads: 2 d-columns each; swizzled read (never wraps: d+4r even)
  {
    int r = tid & 15, dq = tid >> 4;  // consecutive lanes -> consecutive t
    int d = dq * 2;
    float2 qs = {0.f, 0.f};
#pragma unroll
    for (int w = 0; w < NW; ++w) {
      float2 v = *(const float2*)&s_qp[w][r][(d + 4 * r) & 63];
      qs.x += v.x; qs.y += v.y;
    }
    int t = t0 + r;
    float* ob = outq + ((size_t)b << 18) + (size_t)t;
    ob[(size_t)(d + 0) << 12] = qs.x;
    ob[(size_t)(d + 1) << 12] = qs.y;
    float2 xv = *(const float2*)&s_x[r][d];
    float dx0 = xv.x - qs.x, dx1 = xv.y - qs.y;
    partial += 0.5f * precision * (dx0 * dx0 + dx1 * dx1);
  }
#pragma unroll
  for (int off = 32; off; off >>= 1) partial += __shfl_xor(partial, off);
  if (lane == 0) s_red[wl] = partial;
  __syncthreads();
  if (tid == 0) {
    float s = 0.f;
#pragma unroll
    for (int w = 0; w < NW; ++w) s += s_red[w];
    atomicAdd(accum, s);
  }
}

__global__ void vq_finalize(const float* __restrict__ ws, float* __restrict__ out) {
  __shared__ float red[4];
  int tid = threadIdx.x;
  float h = 0.f;
  for (int m = tid; m < M_DIM; m += 256) {
    float avg = ws[M_DIM + m] * (1.0f / 32768.0f);
    h += avg * __logf(avg + 1e-10f);
  }
#pragma unroll
  for (int off = 32; off; off >>= 1) h += __shfl_xor(h, off);
  int lane = tid & 63, wave = tid >> 6;
  if (lane == 0) red[wave] = h;
  __syncthreads();
  if (tid == 0) {
    out[0] = ws[2 * M_DIM] * 0.125f;                        // loss = total / B
    out[1] = __expf(-(red[0] + red[1] + red[2] + red[3]));  // perplexity
  }
}

extern "C" void kernel_launch(void* const* d_in, const int* in_sizes, int n_in,
                              void* d_out, int out_size, void* d_ws, size_t ws_size,
                              hipStream_t stream) {
  const float* x = (const float*)d_in[0];
  const float* emb = (const float*)d_in[1];
  const float* lvq = (const float*)d_in[2];
  const float* gum = (const float*)d_in[3];
  const float* temp = (const float*)d_in[4];
  float* out = (float*)d_out;
  float* ws = (float*)d_ws;

  hipLaunchKernelGGL(vq_conv, dim3(16), dim3(256), 0, stream, emb, ws);
  hipLaunchKernelGGL(vq_main, dim3(N_ROWS / TR), dim3(NT), 0, stream,
                     x, emb, lvq, gum, temp, out, ws);
  hipLaunchKernelGGL(vq_finalize, dim3(1), dim3(256), 0, stream, ws,
                     out + (size_t)2097152);
}